// Round 6
// baseline (502.317 us; speedup 1.0000x reference)
//
#include <hip/hip_runtime.h>
#include <hip/hip_bf16.h>
#include <stdint.h>

#define DIM   1024
#define HID   2048
#define NE    8
#define TTOK  8192
#define BM    128
#define BN    128
#define BK    32
#define RMAX  (TTOK + NE * BM)   /* 9216 padded rows max */
#define MTMAX 72                 /* >= 8192/128 + 7 worst-case m-tiles */

typedef __attribute__((ext_vector_type(8))) short bf16x8;
typedef __attribute__((ext_vector_type(8))) unsigned short u16x8;
typedef __attribute__((ext_vector_type(4))) unsigned short u16x4;
typedef __attribute__((ext_vector_type(4))) float f32x4;

// fp32 -> bf16 round-to-nearest-even on raw bits
__device__ inline unsigned short f2bf(float f) {
    union { float f; unsigned u; } v; v.f = f;
    unsigned r = v.u + 0x7fffu + ((v.u >> 16) & 1u);
    return (unsigned short)(r >> 16);
}

// async global->LDS, 16B per lane; lds base must be wave-uniform.
// R4 lesson: __syncthreads() forces the compiler to drain vmcnt(0) at every
// barrier, serializing any dbuf built on it (119 -> 149 us). R6: pipeline with
// RAW s_barrier + inline-asm counted vmcnt instead (m201/m218 mechanism).
__device__ inline void async_copy16(const void* g, void* l) {
    __builtin_amdgcn_global_load_lds(
        (__attribute__((address_space(1))) void*)(void*)g,
        (__attribute__((address_space(3))) void*)l,
        16, 0, 0);
}

// ---------------- centroid norms (tiny; token-invariant, so NOT in route) ----------------
__global__ __launch_bounds__(256) void cnorm_k(const float* __restrict__ cent,
                                               float* __restrict__ cnorm) {
    int e = blockIdx.x, tid = threadIdx.x;
    float4 cv = ((const float4*)(cent + (size_t)e * DIM))[tid];
    float ss = cv.x * cv.x + cv.y * cv.y + cv.z * cv.z + cv.w * cv.w;
#pragma unroll
    for (int off = 32; off; off >>= 1) ss += __shfl_down(ss, off);
    __shared__ float red[4];
    int w = tid >> 6, l = tid & 63;
    if (l == 0) red[w] = ss;
    __syncthreads();
    if (tid == 0) cnorm[e] = red[0] + red[1] + red[2] + red[3];
}

// ================= fused prep: route and weight transposes =================
// (R3/R5 lesson: transpose BW pinned at ~2.0 TB/s across three structural
// variants — latency/structure-bound, not layout-bound. Untouched.)

__device__ inline void transpose_body(const float* __restrict__ W,
                                      unsigned short* __restrict__ Wt,
                                      int Kd, int Nd, int e, int ntile, int ktile,
                                      unsigned short* tile /* [64*132] shorts */) {
    const float* src = W + (size_t)e * Kd * Nd;
    unsigned short* dst = Wt + (size_t)e * Kd * Nd;
    const int n0 = ntile * 64, k0 = ktile * 128;
    const int t = threadIdx.x;
    const int kr = t >> 4;             // 0..15
    const int nq = (t & 15) * 4;       // 0..60
#pragma unroll
    for (int p = 0; p < 8; ++p) {
        int k = p * 16 + kr;
        float4 v = *(const float4*)(src + (size_t)(k0 + k) * Nd + n0 + nq);
        tile[(nq + 0) * 132 + k] = f2bf(v.x);
        tile[(nq + 1) * 132 + k] = f2bf(v.y);
        tile[(nq + 2) * 132 + k] = f2bf(v.z);
        tile[(nq + 3) * 132 + k] = f2bf(v.w);
    }
    __syncthreads();
    const int r = t >> 2;              // n row 0..63
    const int c = t & 3;               // 32-short k chunk 0..3
    const unsigned short* bsrc = tile + r * 132 + c * 32;
    u16x4 a0 = *(const u16x4*)(bsrc + 0);
    u16x4 a1 = *(const u16x4*)(bsrc + 4);
    u16x4 a2 = *(const u16x4*)(bsrc + 8);
    u16x4 a3 = *(const u16x4*)(bsrc + 12);
    u16x4 a4 = *(const u16x4*)(bsrc + 16);
    u16x4 a5 = *(const u16x4*)(bsrc + 20);
    u16x4 a6 = *(const u16x4*)(bsrc + 24);
    u16x4 a7 = *(const u16x4*)(bsrc + 28);
    u16x8 s0, s1, s2, s3;
#pragma unroll
    for (int i = 0; i < 4; ++i) {
        s0[i] = a0[i]; s0[4 + i] = a1[i];
        s1[i] = a2[i]; s1[4 + i] = a3[i];
        s2[i] = a4[i]; s2[4 + i] = a5[i];
        s3[i] = a6[i]; s3[4 + i] = a7[i];
    }
    unsigned short* drow = dst + (size_t)(n0 + r) * Kd + k0 + c * 32;
    *(u16x8*)(drow + 0)  = s0;         // 64B-aligned
    *(u16x8*)(drow + 8)  = s1;
    *(u16x8*)(drow + 16) = s2;
    *(u16x8*)(drow + 24) = s3;
}

__device__ inline void route_body(const float* __restrict__ x,
                                  const float* __restrict__ scale,
                                  const float* __restrict__ cent,
                                  const float* __restrict__ cnorm,
                                  int* __restrict__ ids,
                                  int* __restrict__ counts,
                                  unsigned short* __restrict__ xn,
                                  int tok, unsigned short* sm) {
    float* redf = (float*)sm;          // [4][10] partials + r at [40]
    const int tid = threadIdx.x;
    float4 xv = ((const float4*)(x + (size_t)tok * DIM))[tid];
    float4 sv = ((const float4*)scale)[tid];
    float4 xs; xs.x = xv.x * sv.x; xs.y = xv.y * sv.y; xs.z = xv.z * sv.z; xs.w = xv.w * sv.w;
    float vals[9];                     // [0]=ss, [1..8]=dot[e]
    vals[0] = xv.x * xv.x + xv.y * xv.y + xv.z * xv.z + xv.w * xv.w;
#pragma unroll
    for (int e = 0; e < NE; ++e) {
        float4 cv = ((const float4*)(cent + (size_t)e * DIM))[tid];
        vals[1 + e] = xs.x * cv.x + xs.y * cv.y + xs.z * cv.z + xs.w * cv.w;
    }
#pragma unroll
    for (int off = 32; off; off >>= 1) {
#pragma unroll
        for (int i = 0; i < 9; ++i) vals[i] += __shfl_down(vals[i], off);
    }
    const int w = tid >> 6, l = tid & 63;
    if (l == 0) {
#pragma unroll
        for (int i = 0; i < 9; ++i) redf[w * 10 + i] = vals[i];
    }
    __syncthreads();
    if (tid == 0) {
        float S = redf[0] + redf[10] + redf[20] + redf[30];
        float r = rsqrtf(S * (1.0f / DIM) + 1e-6f);
        float best = 3.4e38f; int be = 0;
#pragma unroll
        for (int e = 0; e < NE; ++e) {
            float D = redf[1 + e] + redf[10 + 1 + e] + redf[20 + 1 + e] + redf[30 + 1 + e];
            float dist = cnorm[e] - 2.0f * r * D;   // nx term dropped (argmin-invariant)
            if (dist < best) { best = dist; be = e; }
        }
        ids[tok] = be;
        atomicAdd(&counts[be], 1);
        redf[40] = r;
    }
    __syncthreads();
    float r = redf[40];
    ushort4 o;
    o.x = f2bf(xs.x * r); o.y = f2bf(xs.y * r);
    o.z = f2bf(xs.z * r); o.w = f2bf(xs.w * r);
    ((ushort4*)(xn + (size_t)tok * DIM))[tid] = o;
}

// Grid = 2048*7 blocks: stripes 0..2 -> transposes (6144: 4096 up + 2048 down),
// stripes 3..6 -> route (8192).
__global__ __launch_bounds__(256) void prep_k(const float* __restrict__ x,
                                              const float* __restrict__ scale,
                                              const float* __restrict__ cent,
                                              const float* __restrict__ cnorm,
                                              const float* __restrict__ up_w,
                                              const float* __restrict__ down_w,
                                              int* __restrict__ ids,
                                              int* __restrict__ counts,
                                              unsigned short* __restrict__ xn,
                                              unsigned short* __restrict__ upT,
                                              unsigned short* __restrict__ downT) {
    __shared__ __align__(16) unsigned short sm[64 * 132];
    int id = blockIdx.x;
    int q = id / 7;
    int s = id - q * 7;
    if (s < 3) {
        int v = q * 3 + s;                 // 0..6143
        if (v < 4096) {                    // up: e(8) x kt(8) x nt(64), nt fastest
            int rem = v & 511;
            transpose_body(up_w, upT, DIM, 2 * HID, v >> 9, rem & 63, rem >> 6, sm);
        } else {                           // down: e(8) x kt(16) x nt(16), nt fastest
            int wdn = v - 4096;
            int rem = wdn & 255;
            transpose_body(down_w, downT, HID, DIM, wdn >> 8, rem & 15, rem >> 4, sm);
        }
    } else {
        int tok = q * 4 + (s - 3);         // 0..8191
        route_body(x, scale, cent, cnorm, ids, counts, xn, tok, sm);
    }
}

// ------- assign sorted slots; plan recomputed inline from counts -------
__global__ __launch_bounds__(256) void place_k(const int* __restrict__ ids,
                                               const int* __restrict__ counts,
                                               int* __restrict__ cursors,
                                               int* __restrict__ sorted_tok) {
    int tid = threadIdx.x;
    int t = blockIdx.x * 256 + tid;
    int e = ids[t];
    int base = 0;
    {
        int row = 0;
#pragma unroll
        for (int ee = 0; ee < NE; ++ee) {
            if (ee == e) base = row;
            row += (counts[ee] + BM - 1) & ~(BM - 1);
        }
    }
    int lane = tid & 63;
    int pos = 0;
#pragma unroll
    for (int ee = 0; ee < NE; ++ee) {
        unsigned long long grp = __ballot(e == ee);
        if (e == ee) {
            int leader = __ffsll((unsigned long long)grp) - 1;
            int off = 0;
            if (lane == leader) off = atomicAdd(&cursors[ee], (int)__popcll(grp));
            off = __shfl(off, leader);
            pos = base + off + (int)__popcll(grp & ((1ull << lane) - 1ull));
        }
    }
    sorted_tok[pos] = t;
    if (blockIdx.x == 0) {
        int row = 0;
#pragma unroll
        for (int ee = 0; ee < NE; ++ee) {
            int c = counts[ee];
            int seg = (c + BM - 1) & ~(BM - 1);
            for (int i = c + tid; i < seg; i += 256) sorted_tok[row + i] = -1;
            row += seg;
        }
    }
}

// Inline tile map: recompute (e, row0) for tile mt from counts.
__device__ inline bool tile_map(const int* __restrict__ counts, int mt,
                                int& e, int& row0) {
    int4 c0 = ((const int4*)counts)[0];
    int4 c1 = ((const int4*)counts)[1];
    int cc[8] = {c0.x, c0.y, c0.z, c0.w, c1.x, c1.y, c1.z, c1.w};
    e = -1; row0 = 0;
    int acc = 0, row = 0;
#pragma unroll
    for (int ee = 0; ee < NE; ++ee) {
        int tiles = (cc[ee] + BM - 1) >> 7;
        if (e < 0 && mt < acc + tiles) { e = ee; row0 = row + (mt - acc) * BM; }
        acc += tiles; row += tiles * BM;
    }
    return e >= 0;
}

// T1 XCD swizzle (kept from R5: gemm_up -2%, total within noise).
__device__ inline void xcd_tile(int& mt, int& n0) {
    int nwg = gridDim.x * gridDim.y;
    int p   = blockIdx.y * gridDim.x + blockIdx.x;
    int cpx = nwg >> 3;
    int lg  = (p & 7) * cpx + (p >> 3);
    mt = lg % MTMAX;
    n0 = (lg / MTMAX) * BN;
}

// ---------------- up GEMM (dual tile: a & g) + fused swiglu ----------------
// T3 minimum 2-phase with COUNTED vmcnt (m201/m218 mechanism): raw s_barrier
// (no compiler-forced drain), inline-asm vmcnt(6) keeps the next tile's 6
// global_load_lds in flight across the barrier, sched_barrier(0) fences
// ds_reads against hoist/sink (rule #18). Per-iter: [issue next-tile loads,
// vmcnt(6), barrier, compute cur, barrier]. End barrier orders all reads of
// buf[cur] before next iter's DMA overwrite of it.
__global__ __launch_bounds__(256, 2) void gemm_up(const unsigned short* __restrict__ xn,
                                                  const unsigned short* __restrict__ upT,
                                                  unsigned short* __restrict__ act,
                                                  const int* __restrict__ sorted_tok,
                                                  const int* __restrict__ counts) {
    int mt, n0;
    xcd_tile(mt, n0);
    int e, row0;
    if (!tile_map(counts, mt, e, row0)) return;

    __shared__ __align__(16) unsigned short As[2][BM * BK];
    __shared__ __align__(16) unsigned short Ba[2][BM * BK];
    __shared__ __align__(16) unsigned short Bg[2][BM * BK];

    const int tid = threadIdx.x;
    const int w = tid >> 6, l = tid & 63;
    const int rl = l & 15, q = l >> 4;
    const int m_off = (w >> 1) * 64, n_off = (w & 1) * 64;
    const int g0 = 2 * w, g1 = 2 * w + 1;

    const int sr = l >> 2;            // row within 16-row staging group
    const int sc = (l & 3) * 8;       // k-chunk (elements, 16B)

    int tok0 = sorted_tok[row0 + 16 * g0 + sr]; if (tok0 < 0) tok0 = 0;
    int tok1 = sorted_tok[row0 + 16 * g1 + sr]; if (tok1 < 0) tok1 = 0;
    const unsigned short* gA0 = xn + (size_t)tok0 * DIM + sc;
    const unsigned short* gA1 = xn + (size_t)tok1 * DIM + sc;
    const unsigned short* upE = upT + (size_t)e * (2 * HID) * DIM;
    const unsigned short* gBa0 = upE + (size_t)(n0 + 16 * g0 + sr) * DIM + sc;
    const unsigned short* gBa1 = upE + (size_t)(n0 + 16 * g1 + sr) * DIM + sc;
    const unsigned short* gBg0 = upE + (size_t)(HID + n0 + 16 * g0 + sr) * DIM + sc;
    const unsigned short* gBg1 = upE + (size_t)(HID + n0 + 16 * g1 + sr) * DIM + sc;

    f32x4 accA[4][4], accG[4][4];
#pragma unroll
    for (int i = 0; i < 4; ++i)
#pragma unroll
        for (int j = 0; j < 4; ++j) {
            accA[i][j] = (f32x4){0.f, 0.f, 0.f, 0.f};
            accG[i][j] = (f32x4){0.f, 0.f, 0.f, 0.f};
        }

#define STAGE_UP(buf, kt) do { \
        const int _ko = (kt) * BK; \
        async_copy16(gA0 + _ko,  As[buf] + g0 * 512); \
        async_copy16(gA1 + _ko,  As[buf] + g1 * 512); \
        async_copy16(gBa0 + _ko, Ba[buf] + g0 * 512); \
        async_copy16(gBa1 + _ko, Ba[buf] + g1 * 512); \
        async_copy16(gBg0 + _ko, Bg[buf] + g0 * 512); \
        async_copy16(gBg1 + _ko, Bg[buf] + g1 * 512); \
    } while (0)

#define COMPUTE_UP(buf) do { \
        const unsigned short* Ac  = As[buf]; \
        const unsigned short* Bac = Ba[buf]; \
        const unsigned short* Bgc = Bg[buf]; \
        bf16x8 af[4], ba[4], bg[4]; \
        _Pragma("unroll") \
        for (int mi = 0; mi < 4; ++mi) \
            af[mi] = *(const bf16x8*)(Ac + (m_off + mi * 16 + rl) * BK + q * 8); \
        _Pragma("unroll") \
        for (int ni = 0; ni < 4; ++ni) { \
            ba[ni] = *(const bf16x8*)(Bac + (n_off + ni * 16 + rl) * BK + q * 8); \
            bg[ni] = *(const bf16x8*)(Bgc + (n_off + ni * 16 + rl) * BK + q * 8); \
        } \
        _Pragma("unroll") \
        for (int mi = 0; mi < 4; ++mi) \
            _Pragma("unroll") \
            for (int ni = 0; ni < 4; ++ni) { \
                accA[mi][ni] = __builtin_amdgcn_mfma_f32_16x16x32_bf16(af[mi], ba[ni], accA[mi][ni], 0, 0, 0); \
                accG[mi][ni] = __builtin_amdgcn_mfma_f32_16x16x32_bf16(af[mi], bg[ni], accG[mi][ni], 0, 0, 0); \
            } \
    } while (0)

    const int NT = DIM / BK;
    STAGE_UP(0, 0);
    for (int kt = 0; kt < NT - 1; ++kt) {
        const int cur = kt & 1;
        STAGE_UP(cur ^ 1, kt + 1);
        asm volatile("s_waitcnt vmcnt(6)" ::: "memory");
        __builtin_amdgcn_s_barrier();
        __builtin_amdgcn_sched_barrier(0);
        COMPUTE_UP(cur);
        __builtin_amdgcn_sched_barrier(0);
        __builtin_amdgcn_s_barrier();
    }
    asm volatile("s_waitcnt vmcnt(0)" ::: "memory");
    __builtin_amdgcn_s_barrier();
    __builtin_amdgcn_sched_barrier(0);
    COMPUTE_UP((NT - 1) & 1);

#undef STAGE_UP
#undef COMPUTE_UP

    // epilogue: act = a * silu(g), bf16 (pad rows write garbage -> dead)
#pragma unroll
    for (int mi = 0; mi < 4; ++mi)
#pragma unroll
        for (int ni = 0; ni < 4; ++ni)
#pragma unroll
            for (int r = 0; r < 4; ++r) {
                float a = accA[mi][ni][r];
                float g = accG[mi][ni][r];
                float s = a * (g / (1.0f + __expf(-g)));
                int gr = row0 + m_off + mi * 16 + q * 4 + r;
                int gc = n0 + n_off + ni * 16 + rl;
                act[(size_t)gr * HID + gc] = f2bf(s);
            }
}

// ---------------- down GEMM + residual + scatter to d_out ----------------
// Same counted-vmcnt 2-phase; 4 loads/tile -> vmcnt(4).
__global__ __launch_bounds__(256, 2) void gemm_down(const unsigned short* __restrict__ act,
                                                    const unsigned short* __restrict__ downT,
                                                    const int* __restrict__ sorted_tok,
                                                    const int* __restrict__ counts,
                                                    const float* __restrict__ x,
                                                    float* __restrict__ out) {
    int mt, n0;
    xcd_tile(mt, n0);
    int e, row0;
    if (!tile_map(counts, mt, e, row0)) return;

    __shared__ __align__(16) unsigned short As[2][BM * BK];
    __shared__ __align__(16) unsigned short Bs[2][BM * BK];

    const int tid = threadIdx.x;
    const int w = tid >> 6, l = tid & 63;
    const int rl = l & 15, q = l >> 4;
    const int m_off = (w >> 1) * 64, n_off = (w & 1) * 64;
    const int g0 = 2 * w, g1 = 2 * w + 1;

    const int sr = l >> 2;
    const int sc = (l & 3) * 8;

    const unsigned short* gA0 = act + (size_t)(row0 + 16 * g0 + sr) * HID + sc;
    const unsigned short* gA1 = act + (size_t)(row0 + 16 * g1 + sr) * HID + sc;
    const unsigned short* dnE = downT + (size_t)e * DIM * HID;
    const unsigned short* gB0 = dnE + (size_t)(n0 + 16 * g0 + sr) * HID + sc;
    const unsigned short* gB1 = dnE + (size_t)(n0 + 16 * g1 + sr) * HID + sc;

    f32x4 acc[4][4];
#pragma unroll
    for (int i = 0; i < 4; ++i)
#pragma unroll
        for (int j = 0; j < 4; ++j) acc[i][j] = (f32x4){0.f, 0.f, 0.f, 0.f};

#define STAGE_DN(buf, kt) do { \
        const int _ko = (kt) * BK; \
        async_copy16(gA0 + _ko, As[buf] + g0 * 512); \
        async_copy16(gA1 + _ko, As[buf] + g1 * 512); \
        async_copy16(gB0 + _ko, Bs[buf] + g0 * 512); \
        async_copy16(gB1 + _ko, Bs[buf] + g1 * 512); \
    } while (0)

#define COMPUTE_DN(buf) do { \
        const unsigned short* Ac = As[buf]; \
        const unsigned short* Bc = Bs[buf]; \
        bf16x8 af[4], bf[4]; \
        _Pragma("unroll") \
        for (int mi = 0; mi < 4; ++mi) \
            af[mi] = *(const bf16x8*)(Ac + (m_off + mi * 16 + rl) * BK + q * 8); \
        _Pragma("unroll") \
        for (int ni = 0; ni < 4; ++ni) \
            bf[ni] = *(const bf16x8*)(Bc + (n_off + ni * 16 + rl) * BK + q * 8); \
        _Pragma("unroll") \
        for (int mi = 0; mi < 4; ++mi) \
            _Pragma("unroll") \
            for (int ni = 0; ni < 4; ++ni) \
                acc[mi][ni] = __builtin_amdgcn_mfma_f32_16x16x32_bf16(af[mi], bf[ni], acc[mi][ni], 0, 0, 0); \
    } while (0)

    const int NT = HID / BK;
    STAGE_DN(0, 0);
    for (int kt = 0; kt < NT - 1; ++kt) {
        const int cur = kt & 1;
        STAGE_DN(cur ^ 1, kt + 1);
        asm volatile("s_waitcnt vmcnt(4)" ::: "memory");
        __builtin_amdgcn_s_barrier();
        __builtin_amdgcn_sched_barrier(0);
        COMPUTE_DN(cur);
        __builtin_amdgcn_sched_barrier(0);
        __builtin_amdgcn_s_barrier();
    }
    asm volatile("s_waitcnt vmcnt(0)" ::: "memory");
    __builtin_amdgcn_s_barrier();
    __builtin_amdgcn_sched_barrier(0);
    COMPUTE_DN((NT - 1) & 1);

#undef STAGE_DN
#undef COMPUTE_DN

    // epilogue: out[tok] = y + x[tok]; skip padding rows (tok = -1)
#pragma unroll
    for (int mi = 0; mi < 4; ++mi)
#pragma unroll
        for (int r = 0; r < 4; ++r) {
            int gr = row0 + m_off + mi * 16 + q * 4 + r;
            int tok = sorted_tok[gr];
            if (tok >= 0) {
#pragma unroll
                for (int ni = 0; ni < 4; ++ni) {
                    int gc = n0 + n_off + ni * 16 + rl;
                    size_t idx = (size_t)tok * DIM + gc;
                    out[idx] = acc[mi][ni][r] + x[idx];
                }
            }
        }
}

extern "C" void kernel_launch(void* const* d_in, const int* in_sizes, int n_in,
                              void* d_out, int out_size, void* d_ws, size_t ws_size,
                              hipStream_t stream) {
    const float* x      = (const float*)d_in[0];
    const float* scale  = (const float*)d_in[1];
    const float* cent   = (const float*)d_in[2];
    const float* up_w   = (const float*)d_in[3];
    const float* down_w = (const float*)d_in[4];
    float* out = (float*)d_out;
    char* ws = (char*)d_ws;

    // ---- workspace layout (bytes) ----
    int*   counts     = (int*)(ws + 0);      // 8
    int*   cursors    = (int*)(ws + 32);     // 8
    float* cnorm      = (float*)(ws + 704);  // 8
    int*   ids        = (int*)(ws + 1024);                   // TTOK
    int*   sorted_tok = (int*)(ws + 1024 + TTOK * 4);        // RMAX
    size_t off = 103424;                                     // 256-aligned
    unsigned short* xn    = (unsigned short*)(ws + off);     off += (size_t)TTOK * DIM * 2;
    unsigned short* act   = (unsigned short*)(ws + off);     off += (size_t)RMAX * HID * 2;
    unsigned short* upT   = (unsigned short*)(ws + off);     off += (size_t)NE * 2 * HID * DIM * 2;
    unsigned short* downT = (unsigned short*)(ws + off);     off += (size_t)NE * DIM * HID * 2;

    (void)hipMemsetAsync(ws, 0, 1024, stream);   // counts/cursors/meta

    cnorm_k<<<NE, 256, 0, stream>>>(cent, cnorm);
    prep_k<<<2048 * 7, 256, 0, stream>>>(x, scale, cent, cnorm, up_w, down_w,
                                         ids, counts, xn, upT, downT);
    place_k<<<TTOK / 256, 256, 0, stream>>>(ids, counts, cursors, sorted_tok);

    gemm_up<<<dim3(MTMAX, HID / BN), 256, 0, stream>>>(xn, upT, act, sorted_tok, counts);
    gemm_down<<<dim3(MTMAX, DIM / BN), 256, 0, stream>>>(act, downT, sorted_tok, counts, x, out);
}

// Round 7
// 502.041 us; speedup vs baseline: 1.0006x; 1.0006x over previous
//
#include <hip/hip_runtime.h>
#include <hip/hip_bf16.h>
#include <stdint.h>

#define DIM   1024
#define HID   2048
#define NE    8
#define TTOK  8192
#define BM    128
#define BN    128
#define BK    64                 /* R7: split [2][BM][32] layout, ks-sequential */
#define RMAX  (TTOK + NE * BM)   /* 9216 padded rows max */
#define MTMAX 72                 /* >= 8192/128 + 7 worst-case m-tiles */

typedef __attribute__((ext_vector_type(8))) short bf16x8;
typedef __attribute__((ext_vector_type(8))) unsigned short u16x8;
typedef __attribute__((ext_vector_type(4))) unsigned short u16x4;
typedef __attribute__((ext_vector_type(4))) float f32x4;

// fp32 -> bf16 round-to-nearest-even on raw bits
__device__ inline unsigned short f2bf(float f) {
    union { float f; unsigned u; } v; v.f = f;
    unsigned r = v.u + 0x7fffu + ((v.u >> 16) & 1u);
    return (unsigned short)(r >> 16);
}

// async global->LDS, 16B per lane; lds base must be wave-uniform.
// R4/R6 lessons: dbuf over this is null-to-negative on the 128^2 2-barrier
// structure (compiler drain in R4; counted-vmcnt neutral in R6, matching the
// m97-ladder regime gate). Serial loop + fewer/bigger K-steps instead.
__device__ inline void async_copy16(const void* g, void* l) {
    __builtin_amdgcn_global_load_lds(
        (__attribute__((address_space(1))) void*)(void*)g,
        (__attribute__((address_space(3))) void*)l,
        16, 0, 0);
}

// ---------------- centroid norms (tiny; token-invariant, so NOT in route) ----------------
__global__ __launch_bounds__(256) void cnorm_k(const float* __restrict__ cent,
                                               float* __restrict__ cnorm) {
    int e = blockIdx.x, tid = threadIdx.x;
    float4 cv = ((const float4*)(cent + (size_t)e * DIM))[tid];
    float ss = cv.x * cv.x + cv.y * cv.y + cv.z * cv.z + cv.w * cv.w;
#pragma unroll
    for (int off = 32; off; off >>= 1) ss += __shfl_down(ss, off);
    __shared__ float red[4];
    int w = tid >> 6, l = tid & 63;
    if (l == 0) red[w] = ss;
    __syncthreads();
    if (tid == 0) cnorm[e] = red[0] + red[1] + red[2] + red[3];
}

// ---- transpose body: W [Kd][Nd] fp32 -> Wt [Nd][Kd] bf16, tile 64n x 128k ----
// (R3/R5: BW invariant across layout variants — ~2 TB/s; kept as-is.)
__device__ inline void transpose_body(const float* __restrict__ W,
                                      unsigned short* __restrict__ Wt,
                                      int Kd, int Nd, int e, int ntile, int ktile,
                                      unsigned short* tile /* >= 64*132 shorts */) {
    const float* src = W + (size_t)e * Kd * Nd;
    unsigned short* dst = Wt + (size_t)e * Kd * Nd;
    const int n0 = ntile * 64, k0 = ktile * 128;
    const int t = threadIdx.x;
    const int kr = t >> 4;             // 0..15
    const int nq = (t & 15) * 4;       // 0..60
#pragma unroll
    for (int p = 0; p < 8; ++p) {
        int k = p * 16 + kr;
        float4 v = *(const float4*)(src + (size_t)(k0 + k) * Nd + n0 + nq);
        tile[(nq + 0) * 132 + k] = f2bf(v.x);
        tile[(nq + 1) * 132 + k] = f2bf(v.y);
        tile[(nq + 2) * 132 + k] = f2bf(v.z);
        tile[(nq + 3) * 132 + k] = f2bf(v.w);
    }
    __syncthreads();
    const int r = t >> 2;              // n row 0..63
    const int c = t & 3;               // 32-short k chunk 0..3
    const unsigned short* bsrc = tile + r * 132 + c * 32;
    u16x4 a0 = *(const u16x4*)(bsrc + 0);
    u16x4 a1 = *(const u16x4*)(bsrc + 4);
    u16x4 a2 = *(const u16x4*)(bsrc + 8);
    u16x4 a3 = *(const u16x4*)(bsrc + 12);
    u16x4 a4 = *(const u16x4*)(bsrc + 16);
    u16x4 a5 = *(const u16x4*)(bsrc + 20);
    u16x4 a6 = *(const u16x4*)(bsrc + 24);
    u16x4 a7 = *(const u16x4*)(bsrc + 28);
    u16x8 s0, s1, s2, s3;
#pragma unroll
    for (int i = 0; i < 4; ++i) {
        s0[i] = a0[i]; s0[4 + i] = a1[i];
        s1[i] = a2[i]; s1[4 + i] = a3[i];
        s2[i] = a4[i]; s2[4 + i] = a5[i];
        s3[i] = a6[i]; s3[4 + i] = a7[i];
    }
    unsigned short* drow = dst + (size_t)(n0 + r) * Kd + k0 + c * 32;
    *(u16x8*)(drow + 0)  = s0;         // 64B-aligned
    *(u16x8*)(drow + 8)  = s1;
    *(u16x8*)(drow + 16) = s2;
    *(u16x8*)(drow + 24) = s3;
}

__device__ inline void route_body(const float* __restrict__ x,
                                  const float* __restrict__ scale,
                                  const float* __restrict__ cent,
                                  const float* __restrict__ cnorm,
                                  int* __restrict__ ids,
                                  int* __restrict__ counts,
                                  unsigned short* __restrict__ xn,
                                  int tok, unsigned short* sm) {
    float* redf = (float*)sm;          // [4][10] partials + r at [40]
    const int tid = threadIdx.x;
    float4 xv = ((const float4*)(x + (size_t)tok * DIM))[tid];
    float4 sv = ((const float4*)scale)[tid];
    float4 xs; xs.x = xv.x * sv.x; xs.y = xv.y * sv.y; xs.z = xv.z * sv.z; xs.w = xv.w * sv.w;
    float vals[9];                     // [0]=ss, [1..8]=dot[e]
    vals[0] = xv.x * xv.x + xv.y * xv.y + xv.z * xv.z + xv.w * xv.w;
#pragma unroll
    for (int e = 0; e < NE; ++e) {
        float4 cv = ((const float4*)(cent + (size_t)e * DIM))[tid];
        vals[1 + e] = xs.x * cv.x + xs.y * cv.y + xs.z * cv.z + xs.w * cv.w;
    }
#pragma unroll
    for (int off = 32; off; off >>= 1) {
#pragma unroll
        for (int i = 0; i < 9; ++i) vals[i] += __shfl_down(vals[i], off);
    }
    const int w = tid >> 6, l = tid & 63;
    if (l == 0) {
#pragma unroll
        for (int i = 0; i < 9; ++i) redf[w * 10 + i] = vals[i];
    }
    __syncthreads();
    if (tid == 0) {
        float S = redf[0] + redf[10] + redf[20] + redf[30];
        float r = rsqrtf(S * (1.0f / DIM) + 1e-6f);
        float best = 3.4e38f; int be = 0;
#pragma unroll
        for (int e = 0; e < NE; ++e) {
            float D = redf[1 + e] + redf[10 + 1 + e] + redf[20 + 1 + e] + redf[30 + 1 + e];
            float dist = cnorm[e] - 2.0f * r * D;   // nx term dropped (argmin-invariant)
            if (dist < best) { best = dist; be = e; }
        }
        ids[tok] = be;
        atomicAdd(&counts[be], 1);
        redf[40] = r;
    }
    __syncthreads();
    float r = redf[40];
    ushort4 o;
    o.x = f2bf(xs.x * r); o.y = f2bf(xs.y * r);
    o.z = f2bf(xs.z * r); o.w = f2bf(xs.w * r);
    ((ushort4*)(xn + (size_t)tok * DIM))[tid] = o;
}

// prep: route + UP transpose only (R7: down-transpose moved into the gemm_up
// dispatch — downT is consumed only by gemm_down, so its ~100MB of traffic
// was serializing in prep's window for no reason).
// Grid = 4096*3: stripe 0 -> up-transpose (4096), stripes 1,2 -> route (8192).
__global__ __launch_bounds__(256) void prep_k(const float* __restrict__ x,
                                              const float* __restrict__ scale,
                                              const float* __restrict__ cent,
                                              const float* __restrict__ cnorm,
                                              const float* __restrict__ up_w,
                                              int* __restrict__ ids,
                                              int* __restrict__ counts,
                                              unsigned short* __restrict__ xn,
                                              unsigned short* __restrict__ upT) {
    __shared__ __align__(16) unsigned short sm[64 * 132];
    int id = blockIdx.x;
    int q = id / 3;
    int s = id - q * 3;
    if (s == 0) {                      // up: e(8) x kt(8) x nt(64), nt fastest
        int rem = q & 511;
        transpose_body(up_w, upT, DIM, 2 * HID, q >> 9, rem & 63, rem >> 6, sm);
    } else {
        int tok = q * 2 + (s - 1);     // 0..8191
        route_body(x, scale, cent, cnorm, ids, counts, xn, tok, sm);
    }
}

// ------- assign sorted slots; plan recomputed inline from counts -------
__global__ __launch_bounds__(256) void place_k(const int* __restrict__ ids,
                                               const int* __restrict__ counts,
                                               int* __restrict__ cursors,
                                               int* __restrict__ sorted_tok) {
    int tid = threadIdx.x;
    int t = blockIdx.x * 256 + tid;
    int e = ids[t];
    int base = 0;
    {
        int row = 0;
#pragma unroll
        for (int ee = 0; ee < NE; ++ee) {
            if (ee == e) base = row;
            row += (counts[ee] + BM - 1) & ~(BM - 1);
        }
    }
    int lane = tid & 63;
    int pos = 0;
#pragma unroll
    for (int ee = 0; ee < NE; ++ee) {
        unsigned long long grp = __ballot(e == ee);
        if (e == ee) {
            int leader = __ffsll((unsigned long long)grp) - 1;
            int off = 0;
            if (lane == leader) off = atomicAdd(&cursors[ee], (int)__popcll(grp));
            off = __shfl(off, leader);
            pos = base + off + (int)__popcll(grp & ((1ull << lane) - 1ull));
        }
    }
    sorted_tok[pos] = t;
    if (blockIdx.x == 0) {
        int row = 0;
#pragma unroll
        for (int ee = 0; ee < NE; ++ee) {
            int c = counts[ee];
            int seg = (c + BM - 1) & ~(BM - 1);
            for (int i = c + tid; i < seg; i += 256) sorted_tok[row + i] = -1;
            row += seg;
        }
    }
}

// Inline tile map: recompute (e, row0) for tile mt from counts.
__device__ inline bool tile_map(const int* __restrict__ counts, int mt,
                                int& e, int& row0) {
    int4 c0 = ((const int4*)counts)[0];
    int4 c1 = ((const int4*)counts)[1];
    int cc[8] = {c0.x, c0.y, c0.z, c0.w, c1.x, c1.y, c1.z, c1.w};
    e = -1; row0 = 0;
    int acc = 0, row = 0;
#pragma unroll
    for (int ee = 0; ee < NE; ++ee) {
        int tiles = (cc[ee] + BM - 1) >> 7;
        if (e < 0 && mt < acc + tiles) { e = ee; row0 = row + (mt - acc) * BM; }
        acc += tiles; row += tiles * BM;
    }
    return e >= 0;
}

// ---------------- up GEMM (dual tile: a & g) + fused swiglu + down-transpose ----------------
// Grid 3200 = 128 groups x 25: stripe 0..8 -> gemm (1152), 9..24 -> down-
// transpose (2048). Transpose blocks (HBM-bound) overlap gemm blocks
// (MFMA-bound) in the same dispatch window; downT completes before gemm_down
// launches (stream order).
// GEMM: BK=64 in split [2][BM][32] ks-major LDS layout — each half keeps 64B
// row pitch (2-way bank alias, free) and quad-contiguous 64B global segments;
// ks processed sequentially so fragment regs don't grow. Drain barriers per
// block: 16 (was 32).
__global__ __launch_bounds__(256, 2) void gemm_up(const unsigned short* __restrict__ xn,
                                                  const unsigned short* __restrict__ upT,
                                                  unsigned short* __restrict__ act,
                                                  const int* __restrict__ sorted_tok,
                                                  const int* __restrict__ counts,
                                                  const float* __restrict__ down_w,
                                                  unsigned short* __restrict__ downT) {
    __shared__ __align__(16) unsigned short smem[3 * 8192];   // 48KB
    int id = blockIdx.x;
    int g25 = id / 25;
    int s = id - g25 * 25;
    if (s >= 9) {                       // down-transpose: e(8) x kt(16) x nt(16)
        int wdn = g25 * 16 + (s - 9);   // 0..2047
        int rem = wdn & 255;
        transpose_body(down_w, downT, HID, DIM, wdn >> 8, rem & 15, rem >> 4, smem);
        return;
    }
    int p = g25 * 9 + s;                // 0..1151
    // T1 XCD swizzle over the 1152 gemm blocks (1152 % 8 == 0, bijective)
    int lg = (p & 7) * (1152 / 8) + (p >> 3);
    int mt = lg % MTMAX;
    int n0 = (lg / MTMAX) * BN;
    int e, row0;
    if (!tile_map(counts, mt, e, row0)) return;

    unsigned short* As = smem;              // [2][128][32]
    unsigned short* Ba = smem + 8192;       // [2][128][32]
    unsigned short* Bg = smem + 16384;      // [2][128][32]

    const int tid = threadIdx.x;
    const int w = tid >> 6, l = tid & 63;
    const int rl = l & 15, q = l >> 4;
    const int m_off = (w >> 1) * 64, n_off = (w & 1) * 64;
    const int g0 = 2 * w, g1 = 2 * w + 1;

    const int sr = l >> 2;            // row within 16-row staging group
    const int sc = (l & 3) * 8;       // k-chunk within 32 (16B)

    int tok0 = sorted_tok[row0 + 16 * g0 + sr]; if (tok0 < 0) tok0 = 0;
    int tok1 = sorted_tok[row0 + 16 * g1 + sr]; if (tok1 < 0) tok1 = 0;
    const unsigned short* gA0 = xn + (size_t)tok0 * DIM + sc;
    const unsigned short* gA1 = xn + (size_t)tok1 * DIM + sc;
    const unsigned short* upE = upT + (size_t)e * (2 * HID) * DIM;
    const unsigned short* gBa0 = upE + (size_t)(n0 + 16 * g0 + sr) * DIM + sc;
    const unsigned short* gBa1 = upE + (size_t)(n0 + 16 * g1 + sr) * DIM + sc;
    const unsigned short* gBg0 = upE + (size_t)(HID + n0 + 16 * g0 + sr) * DIM + sc;
    const unsigned short* gBg1 = upE + (size_t)(HID + n0 + 16 * g1 + sr) * DIM + sc;

    f32x4 accA[4][4], accG[4][4];
#pragma unroll
    for (int i = 0; i < 4; ++i)
#pragma unroll
        for (int j = 0; j < 4; ++j) {
            accA[i][j] = (f32x4){0.f, 0.f, 0.f, 0.f};
            accG[i][j] = (f32x4){0.f, 0.f, 0.f, 0.f};
        }

    const int NT = DIM / BK;          // 16
    for (int kt = 0; kt < NT; ++kt) {
        if (kt) __syncthreads();
        const int ko = kt * BK;
        // stage both ks halves: dest ks*4096 + g*512, global +ks*32
#pragma unroll
        for (int ks = 0; ks < 2; ++ks) {
            const int go = ko + ks * 32, lo = ks * 4096;
            async_copy16(gA0 + go,  As + lo + g0 * 512);
            async_copy16(gA1 + go,  As + lo + g1 * 512);
            async_copy16(gBa0 + go, Ba + lo + g0 * 512);
            async_copy16(gBa1 + go, Ba + lo + g1 * 512);
            async_copy16(gBg0 + go, Bg + lo + g0 * 512);
            async_copy16(gBg1 + go, Bg + lo + g1 * 512);
        }
        __syncthreads();

#pragma unroll
        for (int ks = 0; ks < 2; ++ks) {
            const int lo = ks * 4096;
            bf16x8 af[4], ba[4], bg[4];
#pragma unroll
            for (int mi = 0; mi < 4; ++mi)
                af[mi] = *(const bf16x8*)(As + lo + (m_off + mi * 16 + rl) * 32 + q * 8);
#pragma unroll
            for (int ni = 0; ni < 4; ++ni) {
                ba[ni] = *(const bf16x8*)(Ba + lo + (n_off + ni * 16 + rl) * 32 + q * 8);
                bg[ni] = *(const bf16x8*)(Bg + lo + (n_off + ni * 16 + rl) * 32 + q * 8);
            }
#pragma unroll
            for (int mi = 0; mi < 4; ++mi)
#pragma unroll
                for (int ni = 0; ni < 4; ++ni) {
                    accA[mi][ni] = __builtin_amdgcn_mfma_f32_16x16x32_bf16(af[mi], ba[ni], accA[mi][ni], 0, 0, 0);
                    accG[mi][ni] = __builtin_amdgcn_mfma_f32_16x16x32_bf16(af[mi], bg[ni], accG[mi][ni], 0, 0, 0);
                }
        }
    }

    // epilogue: act = a * silu(g), bf16 (pad rows write garbage -> dead)
#pragma unroll
    for (int mi = 0; mi < 4; ++mi)
#pragma unroll
        for (int ni = 0; ni < 4; ++ni)
#pragma unroll
            for (int r = 0; r < 4; ++r) {
                float a = accA[mi][ni][r];
                float g = accG[mi][ni][r];
                float sv = a * (g / (1.0f + __expf(-g)));
                int gr = row0 + m_off + mi * 16 + q * 4 + r;
                int gc = n0 + n_off + ni * 16 + rl;
                act[(size_t)gr * HID + gc] = f2bf(sv);
            }
}

// ---------------- down GEMM + residual + scatter to d_out ----------------
// Same BK=64 split-layout serial loop; drain barriers 32 (was 64).
__global__ __launch_bounds__(256, 2) void gemm_down(const unsigned short* __restrict__ act,
                                                    const unsigned short* __restrict__ downT,
                                                    const int* __restrict__ sorted_tok,
                                                    const int* __restrict__ counts,
                                                    const float* __restrict__ x,
                                                    float* __restrict__ out) {
    // T1 XCD swizzle (576 blocks, 576 % 8 == 0)
    int nwg = gridDim.x * gridDim.y;
    int p   = blockIdx.y * gridDim.x + blockIdx.x;
    int lg  = (p & 7) * (nwg >> 3) + (p >> 3);
    int mt  = lg % MTMAX;
    int n0  = (lg / MTMAX) * BN;
    int e, row0;
    if (!tile_map(counts, mt, e, row0)) return;

    __shared__ __align__(16) unsigned short As[2 * BM * 32];   // [2][128][32]
    __shared__ __align__(16) unsigned short Bs[2 * BM * 32];

    const int tid = threadIdx.x;
    const int w = tid >> 6, l = tid & 63;
    const int rl = l & 15, q = l >> 4;
    const int m_off = (w >> 1) * 64, n_off = (w & 1) * 64;
    const int g0 = 2 * w, g1 = 2 * w + 1;

    const int sr = l >> 2;
    const int sc = (l & 3) * 8;

    const unsigned short* gA0 = act + (size_t)(row0 + 16 * g0 + sr) * HID + sc;
    const unsigned short* gA1 = act + (size_t)(row0 + 16 * g1 + sr) * HID + sc;
    const unsigned short* dnE = downT + (size_t)e * DIM * HID;
    const unsigned short* gB0 = dnE + (size_t)(n0 + 16 * g0 + sr) * HID + sc;
    const unsigned short* gB1 = dnE + (size_t)(n0 + 16 * g1 + sr) * HID + sc;

    f32x4 acc[4][4];
#pragma unroll
    for (int i = 0; i < 4; ++i)
#pragma unroll
        for (int j = 0; j < 4; ++j) acc[i][j] = (f32x4){0.f, 0.f, 0.f, 0.f};

    const int NT = HID / BK;          // 32
    for (int kt = 0; kt < NT; ++kt) {
        if (kt) __syncthreads();
        const int ko = kt * BK;
#pragma unroll
        for (int ks = 0; ks < 2; ++ks) {
            const int go = ko + ks * 32, lo = ks * 4096;
            async_copy16(gA0 + go, As + lo + g0 * 512);
            async_copy16(gA1 + go, As + lo + g1 * 512);
            async_copy16(gB0 + go, Bs + lo + g0 * 512);
            async_copy16(gB1 + go, Bs + lo + g1 * 512);
        }
        __syncthreads();

#pragma unroll
        for (int ks = 0; ks < 2; ++ks) {
            const int lo = ks * 4096;
            bf16x8 af[4], bf[4];
#pragma unroll
            for (int mi = 0; mi < 4; ++mi)
                af[mi] = *(const bf16x8*)(As + lo + (m_off + mi * 16 + rl) * 32 + q * 8);
#pragma unroll
            for (int ni = 0; ni < 4; ++ni)
                bf[ni] = *(const bf16x8*)(Bs + lo + (n_off + ni * 16 + rl) * 32 + q * 8);
#pragma unroll
            for (int mi = 0; mi < 4; ++mi)
#pragma unroll
                for (int ni = 0; ni < 4; ++ni)
                    acc[mi][ni] = __builtin_amdgcn_mfma_f32_16x16x32_bf16(af[mi], bf[ni], acc[mi][ni], 0, 0, 0);
        }
    }

    // epilogue: out[tok] = y + x[tok]; skip padding rows (tok = -1)
#pragma unroll
    for (int mi = 0; mi < 4; ++mi)
#pragma unroll
        for (int r = 0; r < 4; ++r) {
            int gr = row0 + m_off + mi * 16 + q * 4 + r;
            int tok = sorted_tok[gr];
            if (tok >= 0) {
#pragma unroll
                for (int ni = 0; ni < 4; ++ni) {
                    int gc = n0 + n_off + ni * 16 + rl;
                    size_t idx = (size_t)tok * DIM + gc;
                    out[idx] = acc[mi][ni][r] + x[idx];
                }
            }
        }
}

extern "C" void kernel_launch(void* const* d_in, const int* in_sizes, int n_in,
                              void* d_out, int out_size, void* d_ws, size_t ws_size,
                              hipStream_t stream) {
    const float* x      = (const float*)d_in[0];
    const float* scale  = (const float*)d_in[1];
    const float* cent   = (const float*)d_in[2];
    const float* up_w   = (const float*)d_in[3];
    const float* down_w = (const float*)d_in[4];
    float* out = (float*)d_out;
    char* ws = (char*)d_ws;

    // ---- workspace layout (bytes) ----
    int*   counts     = (int*)(ws + 0);      // 8
    int*   cursors    = (int*)(ws + 32);     // 8
    float* cnorm      = (float*)(ws + 704);  // 8
    int*   ids        = (int*)(ws + 1024);                   // TTOK
    int*   sorted_tok = (int*)(ws + 1024 + TTOK * 4);        // RMAX
    size_t off = 103424;                                     // 256-aligned
    unsigned short* xn    = (unsigned short*)(ws + off);     off += (size_t)TTOK * DIM * 2;
    unsigned short* act   = (unsigned short*)(ws + off);     off += (size_t)RMAX * HID * 2;
    unsigned short* upT   = (unsigned short*)(ws + off);     off += (size_t)NE * 2 * HID * DIM * 2;
    unsigned short* downT = (unsigned short*)(ws + off);     off += (size_t)NE * DIM * HID * 2;

    (void)hipMemsetAsync(ws, 0, 1024, stream);   // counts/cursors/meta

    cnorm_k<<<NE, 256, 0, stream>>>(cent, cnorm);
    prep_k<<<4096 * 3, 256, 0, stream>>>(x, scale, cent, cnorm, up_w,
                                         ids, counts, xn, upT);
    place_k<<<TTOK / 256, 256, 0, stream>>>(ids, counts, cursors, sorted_tok);

    gemm_up<<<3200, 256, 0, stream>>>(xn, upT, act, sorted_tok, counts, down_w, downT);
    gemm_down<<<dim3(MTMAX, DIM / BN), 256, 0, stream>>>(act, downT, sorted_tok, counts, x, out);
}

// Round 8
// 499.878 us; speedup vs baseline: 1.0049x; 1.0043x over previous
//
#include <hip/hip_runtime.h>
#include <hip/hip_bf16.h>
#include <stdint.h>

#define DIM   1024
#define HID   2048
#define NE    8
#define TTOK  8192
#define BM    128
#define BN    128
#define BK    64                 /* split [2][BM][32] layout, ks-sequential */
#define RMAX  (TTOK + NE * BM)   /* 9216 padded rows max */
#define MTMAX 72                 /* >= 8192/128 + 7 worst-case m-tiles */
#define UP_TILES (MTMAX * (HID / BN))   /* 1152 */
#define DN_TILES (MTMAX * (DIM / BN))   /* 576 */

typedef __attribute__((ext_vector_type(8))) short bf16x8;
typedef __attribute__((ext_vector_type(8))) unsigned short u16x8;
typedef __attribute__((ext_vector_type(4))) unsigned short u16x4;
typedef __attribute__((ext_vector_type(4))) float f32x4;

// fp32 -> bf16 round-to-nearest-even on raw bits
__device__ inline unsigned short f2bf(float f) {
    union { float f; unsigned u; } v; v.f = f;
    unsigned r = v.u + 0x7fffu + ((v.u >> 16) & 1u);
    return (unsigned short)(r >> 16);
}

// async global->LDS, 16B per lane; lds base must be wave-uniform.
// R4/R6 lessons: dbuf (compiler-waited or counted-vmcnt) is null-to-negative
// on this 128^2 2-barrier structure. R8 lesson target: the recoverable time
// was never in the K-loop — it's grid-tail quantization (576 blocks / 512
// resident slots = ~2x wall for 1.125x work).
__device__ inline void async_copy16(const void* g, void* l) {
    __builtin_amdgcn_global_load_lds(
        (__attribute__((address_space(1))) void*)(void*)g,
        (__attribute__((address_space(3))) void*)l,
        16, 0, 0);
}

// ---------------- centroid norms (tiny; token-invariant, so NOT in route) ----------------
__global__ __launch_bounds__(256) void cnorm_k(const float* __restrict__ cent,
                                               float* __restrict__ cnorm) {
    int e = blockIdx.x, tid = threadIdx.x;
    float4 cv = ((const float4*)(cent + (size_t)e * DIM))[tid];
    float ss = cv.x * cv.x + cv.y * cv.y + cv.z * cv.z + cv.w * cv.w;
#pragma unroll
    for (int off = 32; off; off >>= 1) ss += __shfl_down(ss, off);
    __shared__ float red[4];
    int w = tid >> 6, l = tid & 63;
    if (l == 0) red[w] = ss;
    __syncthreads();
    if (tid == 0) cnorm[e] = red[0] + red[1] + red[2] + red[3];
}

// ---- transpose body: W [Kd][Nd] fp32 -> Wt [Nd][Kd] bf16, tile 64n x 128k ----
// (R3/R5: BW invariant across layout variants — ~2 TB/s; kept as-is.)
__device__ inline void transpose_body(const float* __restrict__ W,
                                      unsigned short* __restrict__ Wt,
                                      int Kd, int Nd, int e, int ntile, int ktile,
                                      unsigned short* tile /* >= 64*132 shorts */) {
    const float* src = W + (size_t)e * Kd * Nd;
    unsigned short* dst = Wt + (size_t)e * Kd * Nd;
    const int n0 = ntile * 64, k0 = ktile * 128;
    const int t = threadIdx.x;
    const int kr = t >> 4;             // 0..15
    const int nq = (t & 15) * 4;       // 0..60
#pragma unroll
    for (int p = 0; p < 8; ++p) {
        int k = p * 16 + kr;
        float4 v = *(const float4*)(src + (size_t)(k0 + k) * Nd + n0 + nq);
        tile[(nq + 0) * 132 + k] = f2bf(v.x);
        tile[(nq + 1) * 132 + k] = f2bf(v.y);
        tile[(nq + 2) * 132 + k] = f2bf(v.z);
        tile[(nq + 3) * 132 + k] = f2bf(v.w);
    }
    __syncthreads();
    const int r = t >> 2;              // n row 0..63
    const int c = t & 3;               // 32-short k chunk 0..3
    const unsigned short* bsrc = tile + r * 132 + c * 32;
    u16x4 a0 = *(const u16x4*)(bsrc + 0);
    u16x4 a1 = *(const u16x4*)(bsrc + 4);
    u16x4 a2 = *(const u16x4*)(bsrc + 8);
    u16x4 a3 = *(const u16x4*)(bsrc + 12);
    u16x4 a4 = *(const u16x4*)(bsrc + 16);
    u16x4 a5 = *(const u16x4*)(bsrc + 20);
    u16x4 a6 = *(const u16x4*)(bsrc + 24);
    u16x4 a7 = *(const u16x4*)(bsrc + 28);
    u16x8 s0, s1, s2, s3;
#pragma unroll
    for (int i = 0; i < 4; ++i) {
        s0[i] = a0[i]; s0[4 + i] = a1[i];
        s1[i] = a2[i]; s1[4 + i] = a3[i];
        s2[i] = a4[i]; s2[4 + i] = a5[i];
        s3[i] = a6[i]; s3[4 + i] = a7[i];
    }
    unsigned short* drow = dst + (size_t)(n0 + r) * Kd + k0 + c * 32;
    *(u16x8*)(drow + 0)  = s0;         // 64B-aligned
    *(u16x8*)(drow + 8)  = s1;
    *(u16x8*)(drow + 16) = s2;
    *(u16x8*)(drow + 24) = s3;
}

__device__ inline void route_body(const float* __restrict__ x,
                                  const float* __restrict__ scale,
                                  const float* __restrict__ cent,
                                  const float* __restrict__ cnorm,
                                  int* __restrict__ ids,
                                  int* __restrict__ counts,
                                  unsigned short* __restrict__ xn,
                                  int tok, unsigned short* sm) {
    float* redf = (float*)sm;          // [4][10] partials + r at [40]
    const int tid = threadIdx.x;
    float4 xv = ((const float4*)(x + (size_t)tok * DIM))[tid];
    float4 sv = ((const float4*)scale)[tid];
    float4 xs; xs.x = xv.x * sv.x; xs.y = xv.y * sv.y; xs.z = xv.z * sv.z; xs.w = xv.w * sv.w;
    float vals[9];                     // [0]=ss, [1..8]=dot[e]
    vals[0] = xv.x * xv.x + xv.y * xv.y + xv.z * xv.z + xv.w * xv.w;
#pragma unroll
    for (int e = 0; e < NE; ++e) {
        float4 cv = ((const float4*)(cent + (size_t)e * DIM))[tid];
        vals[1 + e] = xs.x * cv.x + xs.y * cv.y + xs.z * cv.z + xs.w * cv.w;
    }
#pragma unroll
    for (int off = 32; off; off >>= 1) {
#pragma unroll
        for (int i = 0; i < 9; ++i) vals[i] += __shfl_down(vals[i], off);
    }
    const int w = tid >> 6, l = tid & 63;
    if (l == 0) {
#pragma unroll
        for (int i = 0; i < 9; ++i) redf[w * 10 + i] = vals[i];
    }
    __syncthreads();
    if (tid == 0) {
        float S = redf[0] + redf[10] + redf[20] + redf[30];
        float r = rsqrtf(S * (1.0f / DIM) + 1e-6f);
        float best = 3.4e38f; int be = 0;
#pragma unroll
        for (int e = 0; e < NE; ++e) {
            float D = redf[1 + e] + redf[10 + 1 + e] + redf[20 + 1 + e] + redf[30 + 1 + e];
            float dist = cnorm[e] - 2.0f * r * D;   // nx term dropped (argmin-invariant)
            if (dist < best) { best = dist; be = e; }
        }
        ids[tok] = be;
        atomicAdd(&counts[be], 1);
        redf[40] = r;
    }
    __syncthreads();
    float r = redf[40];
    ushort4 o;
    o.x = f2bf(xs.x * r); o.y = f2bf(xs.y * r);
    o.z = f2bf(xs.z * r); o.w = f2bf(xs.w * r);
    ((ushort4*)(xn + (size_t)tok * DIM))[tid] = o;
}

// prep: route + UP transpose (down-transpose lives in the gemm_up dispatch).
// Grid = 4096*3: stripe 0 -> up-transpose (4096), stripes 1,2 -> route (8192).
__global__ __launch_bounds__(256) void prep_k(const float* __restrict__ x,
                                              const float* __restrict__ scale,
                                              const float* __restrict__ cent,
                                              const float* __restrict__ cnorm,
                                              const float* __restrict__ up_w,
                                              int* __restrict__ ids,
                                              int* __restrict__ counts,
                                              unsigned short* __restrict__ xn,
                                              unsigned short* __restrict__ upT) {
    __shared__ __align__(16) unsigned short sm[64 * 132];
    int id = blockIdx.x;
    int q = id / 3;
    int s = id - q * 3;
    if (s == 0) {                      // up: e(8) x kt(8) x nt(64), nt fastest
        int rem = q & 511;
        transpose_body(up_w, upT, DIM, 2 * HID, q >> 9, rem & 63, rem >> 6, sm);
    } else {
        int tok = q * 2 + (s - 1);     // 0..8191
        route_body(x, scale, cent, cnorm, ids, counts, xn, tok, sm);
    }
}

// ------- assign sorted slots; plan recomputed inline from counts -------
__global__ __launch_bounds__(256) void place_k(const int* __restrict__ ids,
                                               const int* __restrict__ counts,
                                               int* __restrict__ cursors,
                                               int* __restrict__ sorted_tok) {
    int tid = threadIdx.x;
    int t = blockIdx.x * 256 + tid;
    int e = ids[t];
    int base = 0;
    {
        int row = 0;
#pragma unroll
        for (int ee = 0; ee < NE; ++ee) {
            if (ee == e) base = row;
            row += (counts[ee] + BM - 1) & ~(BM - 1);
        }
    }
    int lane = tid & 63;
    int pos = 0;
#pragma unroll
    for (int ee = 0; ee < NE; ++ee) {
        unsigned long long grp = __ballot(e == ee);
        if (e == ee) {
            int leader = __ffsll((unsigned long long)grp) - 1;
            int off = 0;
            if (lane == leader) off = atomicAdd(&cursors[ee], (int)__popcll(grp));
            off = __shfl(off, leader);
            pos = base + off + (int)__popcll(grp & ((1ull << lane) - 1ull));
        }
    }
    sorted_tok[pos] = t;
    if (blockIdx.x == 0) {
        int row = 0;
#pragma unroll
        for (int ee = 0; ee < NE; ++ee) {
            int c = counts[ee];
            int seg = (c + BM - 1) & ~(BM - 1);
            for (int i = c + tid; i < seg; i += 256) sorted_tok[row + i] = -1;
            row += seg;
        }
    }
}

// Inline tile map: recompute (e, row0) for tile mt from counts.
__device__ inline bool tile_map(const int* __restrict__ counts, int mt,
                                int& e, int& row0) {
    int4 c0 = ((const int4*)counts)[0];
    int4 c1 = ((const int4*)counts)[1];
    int cc[8] = {c0.x, c0.y, c0.z, c0.w, c1.x, c1.y, c1.z, c1.w};
    e = -1; row0 = 0;
    int acc = 0, row = 0;
#pragma unroll
    for (int ee = 0; ee < NE; ++ee) {
        int tiles = (cc[ee] + BM - 1) >> 7;
        if (e < 0 && mt < acc + tiles) { e = ee; row0 = row + (mt - acc) * BM; }
        acc += tiles; row += tiles * BM;
    }
    return e >= 0;
}

// ---------------- up GEMM (dual tile: a & g) + fused swiglu + down-transpose ----------------
// R8: PERSISTENT gemm blocks with atomic work-stealing. 1152 uniform tiles on
// 512 resident slots previously cost ~3 rounds of wall for 2.25 rounds of
// work (tail quantization); stealing lets the first ~512 gemm slot-blocks do
// everything while late slot-blocks exit instantly. Transposes stay stripe-
// interleaved so they backfill the same dispatch window. The per-tile
// __syncthreads() that broadcasts the stolen index doubles as the LDS
// write-hazard fence between tiles.
__global__ __launch_bounds__(256, 2) void gemm_up(const unsigned short* __restrict__ xn,
                                                  const unsigned short* __restrict__ upT,
                                                  unsigned short* __restrict__ act,
                                                  const int* __restrict__ sorted_tok,
                                                  const int* __restrict__ counts,
                                                  const float* __restrict__ down_w,
                                                  unsigned short* __restrict__ downT,
                                                  int* __restrict__ work_ctr) {
    __shared__ __align__(16) unsigned short smem[3 * 8192];   // 48KB
    int id = blockIdx.x;
    int g25 = id / 25;
    int s = id - g25 * 25;
    if (s >= 9) {                       // down-transpose: e(8) x kt(16) x nt(16)
        int wdn = g25 * 16 + (s - 9);   // 0..2047
        int rem = wdn & 255;
        transpose_body(down_w, downT, HID, DIM, wdn >> 8, rem & 15, rem >> 4, smem);
        return;
    }

    unsigned short* As = smem;              // [2ks][128][32]
    unsigned short* Ba = smem + 8192;
    unsigned short* Bg = smem + 16384;
    __shared__ int s_idx;

    const int tid = threadIdx.x;
    const int w = tid >> 6, l = tid & 63;
    const int rl = l & 15, q = l >> 4;
    const int m_off = (w >> 1) * 64, n_off = (w & 1) * 64;
    const int g0 = 2 * w, g1 = 2 * w + 1;
    const int sr = l >> 2;            // row within 16-row staging group
    const int sc = (l & 3) * 8;       // k-chunk within 32 (16B)

    for (;;) {
        if (tid == 0) s_idx = atomicAdd(work_ctr, 1);
        __syncthreads();               // broadcast idx + fence prior tile's LDS reads
        const int idx = s_idx;
        if (idx >= UP_TILES) return;
        const int mt = idx % MTMAX;
        const int n0 = (idx / MTMAX) * BN;
        int e, row0;
        if (!tile_map(counts, mt, e, row0)) continue;

        int tok0 = sorted_tok[row0 + 16 * g0 + sr]; if (tok0 < 0) tok0 = 0;
        int tok1 = sorted_tok[row0 + 16 * g1 + sr]; if (tok1 < 0) tok1 = 0;
        const unsigned short* gA0 = xn + (size_t)tok0 * DIM + sc;
        const unsigned short* gA1 = xn + (size_t)tok1 * DIM + sc;
        const unsigned short* upE = upT + (size_t)e * (2 * HID) * DIM;
        const unsigned short* gBa0 = upE + (size_t)(n0 + 16 * g0 + sr) * DIM + sc;
        const unsigned short* gBa1 = upE + (size_t)(n0 + 16 * g1 + sr) * DIM + sc;
        const unsigned short* gBg0 = upE + (size_t)(HID + n0 + 16 * g0 + sr) * DIM + sc;
        const unsigned short* gBg1 = upE + (size_t)(HID + n0 + 16 * g1 + sr) * DIM + sc;

        f32x4 accA[4][4], accG[4][4];
#pragma unroll
        for (int i = 0; i < 4; ++i)
#pragma unroll
            for (int j = 0; j < 4; ++j) {
                accA[i][j] = (f32x4){0.f, 0.f, 0.f, 0.f};
                accG[i][j] = (f32x4){0.f, 0.f, 0.f, 0.f};
            }

        const int NT = DIM / BK;          // 16
        for (int kt = 0; kt < NT; ++kt) {
            if (kt) __syncthreads();
            const int ko = kt * BK;
#pragma unroll
            for (int ks = 0; ks < 2; ++ks) {
                const int go = ko + ks * 32, lo = ks * 4096;
                async_copy16(gA0 + go,  As + lo + g0 * 512);
                async_copy16(gA1 + go,  As + lo + g1 * 512);
                async_copy16(gBa0 + go, Ba + lo + g0 * 512);
                async_copy16(gBa1 + go, Ba + lo + g1 * 512);
                async_copy16(gBg0 + go, Bg + lo + g0 * 512);
                async_copy16(gBg1 + go, Bg + lo + g1 * 512);
            }
            __syncthreads();

#pragma unroll
            for (int ks = 0; ks < 2; ++ks) {
                const int lo = ks * 4096;
                bf16x8 af[4], ba[4], bg[4];
#pragma unroll
                for (int mi = 0; mi < 4; ++mi)
                    af[mi] = *(const bf16x8*)(As + lo + (m_off + mi * 16 + rl) * 32 + q * 8);
#pragma unroll
                for (int ni = 0; ni < 4; ++ni) {
                    ba[ni] = *(const bf16x8*)(Ba + lo + (n_off + ni * 16 + rl) * 32 + q * 8);
                    bg[ni] = *(const bf16x8*)(Bg + lo + (n_off + ni * 16 + rl) * 32 + q * 8);
                }
#pragma unroll
                for (int mi = 0; mi < 4; ++mi)
#pragma unroll
                    for (int ni = 0; ni < 4; ++ni) {
                        accA[mi][ni] = __builtin_amdgcn_mfma_f32_16x16x32_bf16(af[mi], ba[ni], accA[mi][ni], 0, 0, 0);
                        accG[mi][ni] = __builtin_amdgcn_mfma_f32_16x16x32_bf16(af[mi], bg[ni], accG[mi][ni], 0, 0, 0);
                    }
            }
        }

        // epilogue: act = a * silu(g), bf16 (pad rows write garbage -> dead)
#pragma unroll
        for (int mi = 0; mi < 4; ++mi)
#pragma unroll
            for (int ni = 0; ni < 4; ++ni)
#pragma unroll
                for (int r = 0; r < 4; ++r) {
                    float a = accA[mi][ni][r];
                    float g = accG[mi][ni][r];
                    float sv = a * (g / (1.0f + __expf(-g)));
                    int gr = row0 + m_off + mi * 16 + q * 4 + r;
                    int gc = n0 + n_off + ni * 16 + rl;
                    act[(size_t)gr * HID + gc] = f2bf(sv);
                }
    }
}

// ---------------- down GEMM + residual + scatter to d_out ----------------
// Persistent + work-stealing over 576 tiles (n0-fastest: 8 consecutive steals
// share one hot 0.5MB A-panel). Previously 576 blocks / 512 slots = ~2x wall
// for 1.125x work.
__global__ __launch_bounds__(256, 2) void gemm_down(const unsigned short* __restrict__ act,
                                                    const unsigned short* __restrict__ downT,
                                                    const int* __restrict__ sorted_tok,
                                                    const int* __restrict__ counts,
                                                    const float* __restrict__ x,
                                                    float* __restrict__ out,
                                                    int* __restrict__ work_ctr) {
    __shared__ __align__(16) unsigned short As[2 * BM * 32];   // [2ks][128][32]
    __shared__ __align__(16) unsigned short Bs[2 * BM * 32];
    __shared__ int s_idx;

    const int tid = threadIdx.x;
    const int w = tid >> 6, l = tid & 63;
    const int rl = l & 15, q = l >> 4;
    const int m_off = (w >> 1) * 64, n_off = (w & 1) * 64;
    const int g0 = 2 * w, g1 = 2 * w + 1;
    const int sr = l >> 2;
    const int sc = (l & 3) * 8;

    for (;;) {
        if (tid == 0) s_idx = atomicAdd(work_ctr, 1);
        __syncthreads();               // broadcast idx + fence prior tile's LDS reads
        const int idx = s_idx;
        if (idx >= DN_TILES) return;
        const int n0 = (idx & 7) * BN;   // n0-fastest
        const int mt = idx >> 3;
        int e, row0;
        if (!tile_map(counts, mt, e, row0)) continue;

        const unsigned short* gA0 = act + (size_t)(row0 + 16 * g0 + sr) * HID + sc;
        const unsigned short* gA1 = act + (size_t)(row0 + 16 * g1 + sr) * HID + sc;
        const unsigned short* dnE = downT + (size_t)e * DIM * HID;
        const unsigned short* gB0 = dnE + (size_t)(n0 + 16 * g0 + sr) * HID + sc;
        const unsigned short* gB1 = dnE + (size_t)(n0 + 16 * g1 + sr) * HID + sc;

        f32x4 acc[4][4];
#pragma unroll
        for (int i = 0; i < 4; ++i)
#pragma unroll
            for (int j = 0; j < 4; ++j) acc[i][j] = (f32x4){0.f, 0.f, 0.f, 0.f};

        const int NT = HID / BK;          // 32
        for (int kt = 0; kt < NT; ++kt) {
            if (kt) __syncthreads();
            const int ko = kt * BK;
#pragma unroll
            for (int ks = 0; ks < 2; ++ks) {
                const int go = ko + ks * 32, lo = ks * 4096;
                async_copy16(gA0 + go, As + lo + g0 * 512);
                async_copy16(gA1 + go, As + lo + g1 * 512);
                async_copy16(gB0 + go, Bs + lo + g0 * 512);
                async_copy16(gB1 + go, Bs + lo + g1 * 512);
            }
            __syncthreads();

#pragma unroll
            for (int ks = 0; ks < 2; ++ks) {
                const int lo = ks * 4096;
                bf16x8 af[4], bf[4];
#pragma unroll
                for (int mi = 0; mi < 4; ++mi)
                    af[mi] = *(const bf16x8*)(As + lo + (m_off + mi * 16 + rl) * 32 + q * 8);
#pragma unroll
                for (int ni = 0; ni < 4; ++ni)
                    bf[ni] = *(const bf16x8*)(Bs + lo + (n_off + ni * 16 + rl) * 32 + q * 8);
#pragma unroll
                for (int mi = 0; mi < 4; ++mi)
#pragma unroll
                    for (int ni = 0; ni < 4; ++ni)
                        acc[mi][ni] = __builtin_amdgcn_mfma_f32_16x16x32_bf16(af[mi], bf[ni], acc[mi][ni], 0, 0, 0);
            }
        }

        // epilogue: out[tok] = y + x[tok]; skip padding rows (tok = -1)
#pragma unroll
        for (int mi = 0; mi < 4; ++mi)
#pragma unroll
            for (int r = 0; r < 4; ++r) {
                int gr = row0 + m_off + mi * 16 + q * 4 + r;
                int tok = sorted_tok[gr];
                if (tok >= 0) {
#pragma unroll
                    for (int ni = 0; ni < 4; ++ni) {
                        int gc = n0 + n_off + ni * 16 + rl;
                        size_t idxo = (size_t)tok * DIM + gc;
                        out[idxo] = acc[mi][ni][r] + x[idxo];
                    }
                }
            }
    }
}

extern "C" void kernel_launch(void* const* d_in, const int* in_sizes, int n_in,
                              void* d_out, int out_size, void* d_ws, size_t ws_size,
                              hipStream_t stream) {
    const float* x      = (const float*)d_in[0];
    const float* scale  = (const float*)d_in[1];
    const float* cent   = (const float*)d_in[2];
    const float* up_w   = (const float*)d_in[3];
    const float* down_w = (const float*)d_in[4];
    float* out = (float*)d_out;
    char* ws = (char*)d_ws;

    // ---- workspace layout (bytes) ----
    int*   counts     = (int*)(ws + 0);      // 8
    int*   cursors    = (int*)(ws + 32);     // 8
    int*   ctr_up     = (int*)(ws + 64);     // 1 (work-steal counter)
    int*   ctr_dn     = (int*)(ws + 68);     // 1
    float* cnorm      = (float*)(ws + 704);  // 8
    int*   ids        = (int*)(ws + 1024);                   // TTOK
    int*   sorted_tok = (int*)(ws + 1024 + TTOK * 4);        // RMAX
    size_t off = 103424;                                     // 256-aligned
    unsigned short* xn    = (unsigned short*)(ws + off);     off += (size_t)TTOK * DIM * 2;
    unsigned short* act   = (unsigned short*)(ws + off);     off += (size_t)RMAX * HID * 2;
    unsigned short* upT   = (unsigned short*)(ws + off);     off += (size_t)NE * 2 * HID * DIM * 2;
    unsigned short* downT = (unsigned short*)(ws + off);     off += (size_t)NE * DIM * HID * 2;

    (void)hipMemsetAsync(ws, 0, 1024, stream);   // counts/cursors/counters/meta

    cnorm_k<<<NE, 256, 0, stream>>>(cent, cnorm);
    prep_k<<<4096 * 3, 256, 0, stream>>>(x, scale, cent, cnorm, up_w,
                                         ids, counts, xn, upT);
    place_k<<<TTOK / 256, 256, 0, stream>>>(ids, counts, cursors, sorted_tok);

    gemm_up<<<3200, 256, 0, stream>>>(xn, upT, act, sorted_tok, counts,
                                      down_w, downT, ctr_up);
    gemm_down<<<DN_TILES, 256, 0, stream>>>(act, downT, sorted_tok, counts,
                                            x, out, ctr_dn);
}